// Round 8
// baseline (1865.842 us; speedup 1.0000x reference)
//
#include <hip/hip_runtime.h>
#include <hip/hip_bf16.h>

typedef __attribute__((ext_vector_type(8))) short short8;
typedef __attribute__((ext_vector_type(4))) float f32x4;

__device__ __forceinline__ ushort f2bf(float f) {
    union { float f; uint u; } v; v.f = f;
    uint u = v.u;
    return (ushort)((u + 0x7fffu + ((u >> 16) & 1u)) >> 16);  // RNE
}
__device__ __forceinline__ float bf_lo(uint u) { return __uint_as_float(u << 16); }
__device__ __forceinline__ float bf_hi(uint u) { return __uint_as_float(u & 0xffff0000u); }
__device__ __forceinline__ float lane_bcast_f(float v, int j) {
    return __uint_as_float(__builtin_amdgcn_readlane(__float_as_uint(v), j));
}

// ---------------------------------------------------------------------------
// bf16 MFMA GEMM body (gemm1 only): Y[n,128](bf16) = X[n,128](f32) @ Wt[128][128]
// ---------------------------------------------------------------------------
template <int COLS, bool F32IN>
__device__ __forceinline__ void gemm_body(const void* __restrict__ Xin,
                                          const ushort* __restrict__ Wt,
                                          ushort* __restrict__ Y, int n,
                                          int bid, char* smem) {
    constexpr int LDW = 136;  // +8 pad
    ushort* sX = (ushort*)smem;
    ushort* sW = sX + 64 * LDW;
    const int tid = threadIdx.x;
    const int row0 = bid * 64;

    if (F32IN) {
        const float* Xf = (const float*)Xin;
#pragma unroll
        for (int i = 0; i < 8; ++i) {
            int idx = i * 256 + tid;
            int r = idx >> 5, kc = idx & 31;
            int gr = min(row0 + r, n - 1);
            float4 v = *(const float4*)&Xf[(size_t)gr * 128 + kc * 4];
            ushort4 o;
            o.x = f2bf(v.x); o.y = f2bf(v.y); o.z = f2bf(v.z); o.w = f2bf(v.w);
            *(ushort4*)&sX[r * LDW + kc * 4] = o;
        }
    } else {
        const ushort* Xb = (const ushort*)Xin;
#pragma unroll
        for (int i = 0; i < 4; ++i) {
            int idx = i * 256 + tid;
            int r = idx >> 4, kc = idx & 15;
            int gr = min(row0 + r, n - 1);
            uint4 v = *(const uint4*)&Xb[(size_t)gr * 128 + kc * 8];
            *(uint4*)&sX[r * LDW + kc * 8] = v;
        }
    }
#pragma unroll
    for (int c = tid; c < COLS * 16; c += 256) {
        int r = c >> 4, kc = c & 15;
        uint4 v = *(const uint4*)&Wt[(size_t)r * 128 + kc * 8];
        *(uint4*)&sW[r * LDW + kc * 8] = v;
    }
    __syncthreads();

    constexpr int NT = (COLS == 128) ? 2 : 1;
    constexpr int WN = COLS / 4;
    const int w = tid >> 6;
    const int lane = tid & 63;
    const int lm = lane & 15;
    const int kq = lane >> 4;

    f32x4 acc[4][NT];
#pragma unroll
    for (int mt = 0; mt < 4; ++mt)
#pragma unroll
        for (int ntn = 0; ntn < NT; ++ntn) acc[mt][ntn] = (f32x4){0.f, 0.f, 0.f, 0.f};

#pragma unroll
    for (int ks = 0; ks < 4; ++ks) {
        const int k0 = ks * 32 + kq * 8;
        short8 bfr[NT];
#pragma unroll
        for (int ntn = 0; ntn < NT; ++ntn)
            bfr[ntn] = *(const short8*)&sW[(w * WN + ntn * 16 + lm) * LDW + k0];
#pragma unroll
        for (int mt = 0; mt < 4; ++mt) {
            short8 afr = *(const short8*)&sX[(mt * 16 + lm) * LDW + k0];
#pragma unroll
            for (int ntn = 0; ntn < NT; ++ntn)
                acc[mt][ntn] = __builtin_amdgcn_mfma_f32_16x16x32_bf16(afr, bfr[ntn], acc[mt][ntn], 0, 0, 0);
        }
    }

#pragma unroll
    for (int mt = 0; mt < 4; ++mt) {
        int r_base = row0 + mt * 16 + kq * 4;
#pragma unroll
        for (int ntn = 0; ntn < NT; ++ntn) {
            int col = w * WN + ntn * 16 + lm;
#pragma unroll
            for (int rr = 0; rr < 4; ++rr) {
                int r = r_base + rr;
                if (r < n) Y[(size_t)r * COLS + col] = f2bf(acc[mt][ntn][rr]);
            }
        }
    }
}

// ---------------------------------------------------------------------------
// Phase 1: coarse partition by dst>>6 (64-node buckets) + weight-cast tail.
// Edges packed (dst<<16)|src. LDS atomics only.
// ---------------------------------------------------------------------------
#define PCHUNK 1024
#define NBUCK_MAX 1024

__global__ __launch_bounds__(256) void k_partition(const int* __restrict__ src,
                                                   const int* __restrict__ dst, int E,
                                                   int nbuck, int cap, int pblocks,
                                                   int* __restrict__ gcur,
                                                   uint* __restrict__ part,
                                                   const float* __restrict__ W1,
                                                   const float* __restrict__ W2,
                                                   const float* __restrict__ W3,
                                                   ushort* __restrict__ wt1,
                                                   ushort* __restrict__ wt2,
                                                   ushort* __restrict__ wt3) {
    __shared__ int hist[NBUCK_MAX];
    __shared__ int base[NBUCK_MAX];
    __shared__ int cnt2[NBUCK_MAX];
    const int tid = threadIdx.x;

    if ((int)blockIdx.x >= pblocks) {
        int i = (blockIdx.x - pblocks) * 256 + tid;
        if (i < 16384) {
            int k = i >> 7, nn = i & 127;
            wt1[nn * 128 + k] = f2bf(W1[i]);
        } else if (i < 32768) {
            int j = i - 16384;
            int k = j >> 7, nn = j & 127;
            wt2[nn * 128 + k] = f2bf(W2[j]);
        } else if (i < 40960) {
            int j = i - 32768;
            int k = j >> 6, nn = j & 63;
            wt3[nn * 128 + k] = f2bf(W3[j]);
        }
        return;
    }

    const int s0 = blockIdx.x * PCHUNK;
    const int send = min(s0 + PCHUNK, E);
    for (int i = tid; i < NBUCK_MAX; i += 256) { hist[i] = 0; cnt2[i] = 0; }
    __syncthreads();
    for (int i = s0 + tid; i < send; i += 256) {
        int d = dst[i];
        atomicAdd(&hist[d >> 6], 1);
    }
    __syncthreads();
    for (int j = tid; j < nbuck; j += 256)
        if (hist[j] > 0) base[j] = atomicAdd(&gcur[j], hist[j]);
    __syncthreads();
    for (int i = s0 + tid; i < send; i += 256) {
        int d = dst[i];
        int s = src[i];
        int k = d >> 6;
        int r = base[k] + atomicAdd(&cnt2[k], 1);
        if (r < cap) part[(size_t)k * cap + r] = ((uint)d << 16) | (uint)s;
    }
}

// ---------------------------------------------------------------------------
// Phase 2: degree->dis per bucket (LDS hist, no CSR!) + gemm1 tail blocks.
// ---------------------------------------------------------------------------
__global__ __launch_bounds__(256) void k_dis_gemm1(const uint* __restrict__ part,
                                                   const int* __restrict__ gcur,
                                                   int nbuck, int cap, int n,
                                                   float* __restrict__ dis,
                                                   const float* __restrict__ x,
                                                   const ushort* __restrict__ wt1,
                                                   ushort* __restrict__ bufA) {
    __shared__ char smem[(64 + 128) * 136 * 2];
    const int tid = threadIdx.x;

    if ((int)blockIdx.x >= nbuck) {
        gemm_body<128, true>(x, wt1, bufA, n, blockIdx.x - nbuck, smem);
        return;
    }

    int* hist = (int*)smem;  // 64 ints
    const int b = blockIdx.x;
    const int sz = min(gcur[b], cap);
    const uint* seg = part + (size_t)b * cap;

    if (tid < 64) hist[tid] = 0;
    __syncthreads();
    for (int i = tid; i < sz; i += 256) atomicAdd(&hist[(seg[i] >> 16) & 63], 1);
    __syncthreads();
    int node = b * 64 + tid;
    if (tid < 64 && node < n) dis[node] = rsqrtf((float)(hist[tid] + 1));  // +1 self
}

// ---------------------------------------------------------------------------
// agg_spmm: EDGE-CENTRIC aggregation + fused GEMM. One block = one 64-node
// bucket. Edge phase: stream bucket edge list (coalesced), gather H[src] rows
// (16 independent loads in flight), accumulate into LDS fp32 acc[64][130] via
// native ds_add_f32 (pad lanes masked by weight 0). Then self+bias+relu ->
// bf16 tile (overlaid on acc) -> MFMA with B-frags from global Wt.
// Epilogue pre-scales output rows by dis[r] for the next (weight-free) agg.
// WITHDIS: per-edge dis[src] weight (layer 1; input unscaled).
// ---------------------------------------------------------------------------
template <int COUT, bool WITHDIS>
__global__ __launch_bounds__(256) void agg_spmm(const ushort* __restrict__ H,
                                                const float* __restrict__ dis,
                                                const uint* __restrict__ part,
                                                const int* __restrict__ gcur, int cap,
                                                const float* __restrict__ bias,
                                                const ushort* __restrict__ Wt,
                                                ushort* __restrict__ Y, int n) {
    constexpr int ASTR = 130;              // f32 row stride (pad: banks spread)
    __shared__ char smem[64 * ASTR * 4];   // 33280 B; bf16 tile overlays (17408 B)
    float* accf = (float*)smem;
    ushort* sX = (ushort*)smem;
    const int tid = threadIdx.x;
    const int wid = tid >> 6, lane = tid & 63;
    const int b = blockIdx.x;
    const int row0 = b * 64;
    const uint* Hu = (const uint*)H;       // row = 64 uints (128 bf16)

    {   // zero acc (64*130 = 8320 floats = 2080 float4)
        float4 z = {0.f, 0.f, 0.f, 0.f};
        for (int k = tid; k < 64 * ASTR / 4; k += 256) ((float4*)accf)[k] = z;
    }
    __syncthreads();

    // ---- edge phase ----
    const int sz = min(gcur[b], cap);
    const uint* seg = part + (size_t)b * cap;
    for (int base = wid * 64; base < sz; base += 256) {
        const int i = base + lane;
        const uint p = (i < sz) ? seg[i] : 0u;   // sentinel: row0/node0, w=0
        float w;
        if (WITHDIS) w = (i < sz) ? dis[p & 0xffffu] : 0.0f;
        else         w = (i < sz) ? 1.0f : 0.0f;
        const int c = min(sz - base, 64);
#pragma unroll 1
        for (int j = 0; j < c; j += 16) {        // tail masked by w=0 pads
            uint pv[16]; float wl[16]; uint hv[16];
#pragma unroll
            for (int u = 0; u < 16; ++u) {
                pv[u] = __builtin_amdgcn_readlane(p, j + u);
                wl[u] = lane_bcast_f(w, j + u);
                hv[u] = Hu[(size_t)(pv[u] & 0xffffu) * 64 + lane];
            }
#pragma unroll
            for (int u = 0; u < 16; ++u) {
                int dl = (pv[u] >> 16) & 63;
                float* ap = &accf[dl * ASTR + 2 * lane];
                atomicAdd(ap,     wl[u] * bf_lo(hv[u]));
                atomicAdd(ap + 1, wl[u] * bf_hi(hv[u]));
            }
        }
    }
    __syncthreads();

    // ---- self + bias + relu -> regs ----
    const int row = tid >> 2, q4 = tid & 3;      // thread: row, 32-col quarter
    const int gr = min(row0 + row, n - 1);
    const float dvr = dis[gr];
    uint rpack[16];
#pragma unroll
    for (int k = 0; k < 16; ++k) {
        uint us = Hu[(size_t)gr * 64 + q4 * 16 + k];
        float a0 = accf[row * ASTR + q4 * 32 + 2 * k];
        float a1 = accf[row * ASTR + q4 * 32 + 2 * k + 1];
        float2 bb = ((const float2*)bias)[q4 * 16 + k];
        float s0 = bf_lo(us), s1 = bf_hi(us);
        float r0, r1;
        if (WITHDIS) { r0 = dvr * (a0 + dvr * s0) + bb.x; r1 = dvr * (a1 + dvr * s1) + bb.y; }
        else         { r0 = dvr * (a0 + s0) + bb.x;       r1 = dvr * (a1 + s1) + bb.y; }
        r0 = fmaxf(r0, 0.f); r1 = fmaxf(r1, 0.f);
        rpack[k] = (uint)f2bf(r0) | ((uint)f2bf(r1) << 16);
    }
    __syncthreads();  // all acc reads complete before overlay write
#pragma unroll
    for (int k = 0; k < 16; ++k)
        *(uint*)&sX[row * 136 + q4 * 32 + 2 * k] = rpack[k];
    __syncthreads();

    // ---- MFMA 64 x COUT, B-frags from global Wt ----
    constexpr int NT = COUT / 64;   // 2 (COUT=128) or 1 (COUT=64)
    constexpr int WN = COUT / 4;
    const int lm = lane & 15;
    const int kq = lane >> 4;

    f32x4 acc[4][NT];
#pragma unroll
    for (int mt = 0; mt < 4; ++mt)
#pragma unroll
        for (int ntn = 0; ntn < NT; ++ntn) acc[mt][ntn] = (f32x4){0.f, 0.f, 0.f, 0.f};

#pragma unroll
    for (int ks = 0; ks < 4; ++ks) {
        const int k0 = ks * 32 + kq * 8;
        short8 bfr[NT];
#pragma unroll
        for (int ntn = 0; ntn < NT; ++ntn)
            bfr[ntn] = *(const short8*)&Wt[(size_t)(wid * WN + ntn * 16 + lm) * 128 + k0];
#pragma unroll
        for (int mt = 0; mt < 4; ++mt) {
            short8 afr = *(const short8*)&sX[(mt * 16 + lm) * 136 + k0];
#pragma unroll
            for (int ntn = 0; ntn < NT; ++ntn)
                acc[mt][ntn] = __builtin_amdgcn_mfma_f32_16x16x32_bf16(afr, bfr[ntn], acc[mt][ntn], 0, 0, 0);
        }
    }

    // epilogue: pre-scale rows by dis[r] -> next agg weight-free
#pragma unroll
    for (int mt = 0; mt < 4; ++mt) {
        int r_base = row0 + mt * 16 + kq * 4;
#pragma unroll
        for (int rr = 0; rr < 4; ++rr) {
            int r = r_base + rr;
            if (r < n) {
                float dr = dis[r];
#pragma unroll
                for (int ntn = 0; ntn < NT; ++ntn) {
                    int col = wid * WN + ntn * 16 + lm;
                    Y[(size_t)r * COUT + col] = f2bf(acc[mt][ntn][rr] * dr);
                }
            }
        }
    }
}

// ---------------------------------------------------------------------------
// Final layer: edge-centric agg of bufC (64-col, pre-scaled, weight-free) +
// self + bias + row-normalize -> f32 x_emb. Target MLP fused as tail blocks.
// ---------------------------------------------------------------------------
__global__ __launch_bounds__(256) void agg_final(const ushort* __restrict__ H,
                                                 const float* __restrict__ dis,
                                                 const uint* __restrict__ part,
                                                 const int* __restrict__ gcur,
                                                 int cap, int nbuck,
                                                 const float* __restrict__ bias,
                                                 float* __restrict__ out, int n,
                                                 const float* __restrict__ y,
                                                 const float* __restrict__ gamma,
                                                 const float* __restrict__ beta,
                                                 const float* __restrict__ Wm1,
                                                 const float* __restrict__ bm1,
                                                 const float* __restrict__ Wm2,
                                                 const float* __restrict__ bm2,
                                                 float* __restrict__ out_y) {
    constexpr int ASTR = 66;
    __shared__ char smem[64 * ASTR * 4];  // 16896 B
    const int tid = threadIdx.x;

    if ((int)blockIdx.x >= nbuck) {  // target-MLP tail blocks
        float* red = (float*)smem;
        float* t1 = red + 256;
        float* sv = t1 + 128;  // sv[0]=mu, sv[1]=var
        float yv = y[tid];
        red[tid] = yv;
        __syncthreads();
        for (int s = 128; s > 0; s >>= 1) {
            if (tid < s) red[tid] += red[tid + s];
            __syncthreads();
        }
        if (tid == 0) sv[0] = red[0] * (1.0f / 256.0f);
        __syncthreads();
        float mu = sv[0];
        float d = yv - mu;
        red[tid] = d * d;
        __syncthreads();
        for (int s = 128; s > 0; s >>= 1) {
            if (tid < s) red[tid] += red[tid + s];
            __syncthreads();
        }
        if (tid == 0) sv[1] = red[0] * (1.0f / 256.0f);
        __syncthreads();

        const int row = blockIdx.x - nbuck;
        float yb = (y[row] - mu) * rsqrtf(sv[1] + 1e-5f) * gamma[0] + beta[0];
        if (tid < 128) t1[tid] = fmaxf(yb * Wm1[tid] + bm1[tid], 0.0f);
        __syncthreads();
        if (tid < 64) {
            float acc = bm2[tid];
#pragma unroll 8
            for (int c = 0; c < 128; ++c) acc += t1[c] * Wm2[c * 64 + tid];
            float ss = acc * acc;
#pragma unroll
            for (int m = 1; m < 64; m <<= 1) ss += __shfl_xor(ss, m, 64);
            out_y[row * 64 + tid] = acc / fmaxf(sqrtf(ss), 1e-12f);
        }
        return;
    }

    float* accf = (float*)smem;
    const int wid = tid >> 6, lane = tid & 63;
    const int b = blockIdx.x;
    const int row0 = b * 64;
    const ushort* Hs = H;  // row = 64 bf16

    {   // zero acc (64*66 = 4224 floats = 1056 float4)
        float4 z = {0.f, 0.f, 0.f, 0.f};
        for (int k = tid; k < 64 * ASTR / 4; k += 256) ((float4*)accf)[k] = z;
    }
    __syncthreads();

    const int sz = min(gcur[b], cap);
    const uint* seg = part + (size_t)b * cap;
    for (int base = wid * 64; base < sz; base += 256) {
        const int i = base + lane;
        const uint p = (i < sz) ? seg[i] : 0u;
        const float w = (i < sz) ? 1.0f : 0.0f;
        const int c = min(sz - base, 64);
#pragma unroll 1
        for (int j = 0; j < c; j += 16) {
            uint pv[16]; float wl[16]; uint hv[16];
#pragma unroll
            for (int u = 0; u < 16; ++u) {
                pv[u] = __builtin_amdgcn_readlane(p, j + u);
                wl[u] = lane_bcast_f(w, j + u);
                hv[u] = (uint)Hs[(size_t)(pv[u] & 0xffffu) * 64 + lane];
            }
#pragma unroll
            for (int u = 0; u < 16; ++u) {
                int dl = (pv[u] >> 16) & 63;
                atomicAdd(&accf[dl * ASTR + lane], wl[u] * bf_lo(hv[u]));
            }
        }
    }
    __syncthreads();

    // self + bias + normalize
    const int row = tid >> 2, q4 = tid & 3;  // 16 cols per thread
    const int gr = min(row0 + row, n - 1);
    const float dvr = dis[gr];
    const uint* Hu = (const uint*)H;         // row = 32 uints
    float rr_[16];
    float ss = 0.f;
#pragma unroll
    for (int k = 0; k < 8; ++k) {
        uint us = Hu[(size_t)gr * 32 + q4 * 8 + k];
        float a0 = accf[row * ASTR + q4 * 16 + 2 * k];
        float a1 = accf[row * ASTR + q4 * 16 + 2 * k + 1];
        float2 bb = ((const float2*)bias)[q4 * 8 + k];
        float r0 = dvr * (a0 + bf_lo(us)) + bb.x;
        float r1 = dvr * (a1 + bf_hi(us)) + bb.y;
        ss += r0 * r0 + r1 * r1;
        rr_[2 * k] = r0; rr_[2 * k + 1] = r1;
    }
    ss += __shfl_xor(ss, 1);
    ss += __shfl_xor(ss, 2);
    float inv = 1.0f / fmaxf(sqrtf(ss), 1e-12f);
    if (row0 + row < n) {
        float* op = &out[(size_t)(row0 + row) * 64 + q4 * 16];
#pragma unroll
        for (int k = 0; k < 4; ++k) {
            float4 o = {rr_[4 * k] * inv, rr_[4 * k + 1] * inv,
                        rr_[4 * k + 2] * inv, rr_[4 * k + 3] * inv};
            *(float4*)&op[4 * k] = o;
        }
    }
}

// ---------------------------------------------------------------------------
extern "C" void kernel_launch(void* const* d_in, const int* in_sizes, int n_in,
                              void* d_out, int out_size, void* d_ws, size_t ws_size,
                              hipStream_t stream) {
    const float* x     = (const float*)d_in[0];
    const float* y     = (const float*)d_in[1];
    const int*   edge  = (const int*)d_in[2];
    const float* W1    = (const float*)d_in[3];
    const float* b1    = (const float*)d_in[4];
    const float* W2    = (const float*)d_in[5];
    const float* b2    = (const float*)d_in[6];
    const float* W3    = (const float*)d_in[7];
    const float* b3    = (const float*)d_in[8];
    const float* bng   = (const float*)d_in[9];
    const float* bnb   = (const float*)d_in[10];
    const float* Wm1   = (const float*)d_in[11];
    const float* bm1   = (const float*)d_in[12];
    const float* Wm2   = (const float*)d_in[13];
    const float* bm2   = (const float*)d_in[14];

    const int n = in_sizes[0] / 128;  // 50000
    const int E = in_sizes[2] / 2;    // 800000
    const int* src = edge;
    const int* dst = edge + E;

    const int nbuck = (n + 63) / 64;                   // 782 (64-node buckets)
    const int cap = E / nbuck + E / nbuck / 4 + 1024;  // mean + 25% + slack

    size_t off = 0;
    auto carve = [&](size_t bytes) {
        size_t p = off;
        off = (off + bytes + 255) & ~(size_t)255;
        return p;
    };
    char* ws = (char*)d_ws;
    int*    gcur    = (int*)(ws + carve(NBUCK_MAX * 4));
    uint*   part    = (uint*)(ws + carve((size_t)nbuck * cap * 4));
    float*  dis     = (float*)(ws + carve((size_t)n * 4));
    ushort* wt1     = (ushort*)(ws + carve(128 * 128 * 2));
    ushort* wt2     = (ushort*)(ws + carve(128 * 128 * 2));
    ushort* wt3     = (ushort*)(ws + carve(64 * 128 * 2));
    ushort* bufA    = (ushort*)(ws + carve((size_t)n * 128 * 2));
    ushort* bufB    = (ushort*)(ws + carve((size_t)n * 128 * 2));
    ushort* bufC    = (ushort*)(ws + carve((size_t)n * 64 * 2));
    (void)ws_size; (void)n_in; (void)out_size;

    float* x_emb = (float*)d_out;
    float* y_emb = (float*)d_out + (size_t)n * 64;

    const int pblocks = (E + PCHUNK - 1) / PCHUNK;  // 782
    const int ggrid = (n + 63) / 64;                // 782

    hipMemsetAsync(gcur, 0, NBUCK_MAX * 4, stream);
    k_partition<<<pblocks + 160, 256, 0, stream>>>(src, dst, E, nbuck, cap, pblocks,
                                                   gcur, part, W1, W2, W3, wt1, wt2, wt3);
    // per-bucket degree->dis (782 blocks) + gemm1 (782 blocks) concurrently
    k_dis_gemm1<<<nbuck + ggrid, 256, 0, stream>>>(part, gcur, nbuck, cap, n,
                                                   dis, x, wt1, bufA);

    // layer 1: edge-centric agg (per-edge dis) + GEMM W2 -> bufB pre-scaled
    agg_spmm<128, true><<<nbuck, 256, 0, stream>>>(bufA, dis, part, gcur, cap,
                                                   b1, wt2, bufB, n);
    // layer 2: edge-centric agg (weight-free) + GEMM W3 -> bufC pre-scaled
    agg_spmm<64, false><<<nbuck, 256, 0, stream>>>(bufB, dis, part, gcur, cap,
                                                   b2, wt3, bufC, n);
    // final: edge-centric agg + normalize -> x_emb (+ target MLP tail)
    agg_final<<<nbuck + 256, 256, 0, stream>>>(bufC, dis, part, gcur, cap, nbuck,
                                               b3, x_emb, n,
                                               y, bng, bnb, Wm1, bm1, Wm2, bm2, y_emb);
}

// Round 9
// 243.406 us; speedup vs baseline: 7.6656x; 7.6656x over previous
//
#include <hip/hip_runtime.h>
#include <hip/hip_bf16.h>

typedef __attribute__((ext_vector_type(8))) short short8;
typedef __attribute__((ext_vector_type(4))) float f32x4;

__device__ __forceinline__ ushort f2bf(float f) {
    union { float f; uint u; } v; v.f = f;
    uint u = v.u;
    return (ushort)((u + 0x7fffu + ((u >> 16) & 1u)) >> 16);  // RNE
}
__device__ __forceinline__ float bf_lo(uint u) { return __uint_as_float(u << 16); }
__device__ __forceinline__ float bf_hi(uint u) { return __uint_as_float(u & 0xffff0000u); }
__device__ __forceinline__ float lane_bcast_f(float v, int j) {
    return __uint_as_float(__builtin_amdgcn_readlane(__float_as_uint(v), j));
}

// ---------------------------------------------------------------------------
// bf16 MFMA GEMM body (used by the sort+gemm1 fused kernel only):
// Y[n,COLS](bf16) = X[n,128] @ Wt[COLS][128](bf16)
// smem must be >= (64 + COLS) * 136 * 2 bytes. 256-thread blocks.
// ---------------------------------------------------------------------------
template <int COLS, bool F32IN>
__device__ __forceinline__ void gemm_body(const void* __restrict__ Xin,
                                          const ushort* __restrict__ Wt,
                                          ushort* __restrict__ Y, int n,
                                          int bid, char* smem) {
    constexpr int LDW = 136;  // +8 pad
    ushort* sX = (ushort*)smem;
    ushort* sW = sX + 64 * LDW;
    const int tid = threadIdx.x;
    const int row0 = bid * 64;

    if (F32IN) {
        const float* Xf = (const float*)Xin;
#pragma unroll
        for (int i = 0; i < 8; ++i) {
            int idx = i * 256 + tid;
            int r = idx >> 5, kc = idx & 31;
            int gr = min(row0 + r, n - 1);
            float4 v = *(const float4*)&Xf[(size_t)gr * 128 + kc * 4];
            ushort4 o;
            o.x = f2bf(v.x); o.y = f2bf(v.y); o.z = f2bf(v.z); o.w = f2bf(v.w);
            *(ushort4*)&sX[r * LDW + kc * 4] = o;
        }
    } else {
        const ushort* Xb = (const ushort*)Xin;
#pragma unroll
        for (int i = 0; i < 4; ++i) {
            int idx = i * 256 + tid;
            int r = idx >> 4, kc = idx & 15;
            int gr = min(row0 + r, n - 1);
            uint4 v = *(const uint4*)&Xb[(size_t)gr * 128 + kc * 8];
            *(uint4*)&sX[r * LDW + kc * 8] = v;
        }
    }
#pragma unroll
    for (int c = tid; c < COLS * 16; c += 256) {
        int r = c >> 4, kc = c & 15;
        uint4 v = *(const uint4*)&Wt[(size_t)r * 128 + kc * 8];
        *(uint4*)&sW[r * LDW + kc * 8] = v;
    }
    __syncthreads();

    constexpr int NT = (COLS == 128) ? 2 : 1;
    constexpr int WN = COLS / 4;
    const int w = tid >> 6;
    const int lane = tid & 63;
    const int lm = lane & 15;
    const int kq = lane >> 4;

    f32x4 acc[4][NT];
#pragma unroll
    for (int mt = 0; mt < 4; ++mt)
#pragma unroll
        for (int ntn = 0; ntn < NT; ++ntn) acc[mt][ntn] = (f32x4){0.f, 0.f, 0.f, 0.f};

#pragma unroll
    for (int ks = 0; ks < 4; ++ks) {
        const int k0 = ks * 32 + kq * 8;
        short8 bfr[NT];
#pragma unroll
        for (int ntn = 0; ntn < NT; ++ntn)
            bfr[ntn] = *(const short8*)&sW[(w * WN + ntn * 16 + lm) * LDW + k0];
#pragma unroll
        for (int mt = 0; mt < 4; ++mt) {
            short8 afr = *(const short8*)&sX[(mt * 16 + lm) * LDW + k0];
#pragma unroll
            for (int ntn = 0; ntn < NT; ++ntn)
                acc[mt][ntn] = __builtin_amdgcn_mfma_f32_16x16x32_bf16(afr, bfr[ntn], acc[mt][ntn], 0, 0, 0);
        }
    }

#pragma unroll
    for (int mt = 0; mt < 4; ++mt) {
        int r_base = row0 + mt * 16 + kq * 4;
#pragma unroll
        for (int ntn = 0; ntn < NT; ++ntn) {
            int col = w * WN + ntn * 16 + lm;
#pragma unroll
            for (int rr = 0; rr < 4; ++rr) {
                int r = r_base + rr;
                if (r < n) Y[(size_t)r * COLS + col] = f2bf(acc[mt][ntn][rr]);
            }
        }
    }
}

// ---------------------------------------------------------------------------
// CSR build phase 1: coarse partition by dst>>8 (+fused weight cast tail).
// Edges packed (dst<<16)|src.
// ---------------------------------------------------------------------------
#define PCHUNK 4096

__global__ __launch_bounds__(256) void k_partition(const int* __restrict__ src,
                                                   const int* __restrict__ dst, int E,
                                                   int nbuck, int cap, int pblocks,
                                                   int* __restrict__ gcur,
                                                   uint* __restrict__ part,
                                                   const float* __restrict__ W1,
                                                   const float* __restrict__ W2,
                                                   const float* __restrict__ W3,
                                                   ushort* __restrict__ wt1,
                                                   ushort* __restrict__ wt2,
                                                   ushort* __restrict__ wt3) {
    __shared__ int hist[256];
    __shared__ int base[256];
    __shared__ int cnt2[256];
    const int tid = threadIdx.x;

    if ((int)blockIdx.x >= pblocks) {
        int i = (blockIdx.x - pblocks) * 256 + tid;
        if (i < 16384) {
            int k = i >> 7, nn = i & 127;
            wt1[nn * 128 + k] = f2bf(W1[i]);
        } else if (i < 32768) {
            int j = i - 16384;
            int k = j >> 7, nn = j & 127;
            wt2[nn * 128 + k] = f2bf(W2[j]);
        } else if (i < 40960) {
            int j = i - 32768;
            int k = j >> 6, nn = j & 63;
            wt3[nn * 128 + k] = f2bf(W3[j]);
        }
        return;
    }

    const int s0 = blockIdx.x * PCHUNK;
    const int send = min(s0 + PCHUNK, E);
    hist[tid] = 0;
    cnt2[tid] = 0;
    __syncthreads();
    for (int i = s0 + tid; i < send; i += 256) {
        int d = dst[i];
        atomicAdd(&hist[d >> 8], 1);
    }
    __syncthreads();
    if (tid < nbuck && hist[tid] > 0) base[tid] = atomicAdd(&gcur[tid], hist[tid]);
    __syncthreads();
    for (int i = s0 + tid; i < send; i += 256) {
        int d = dst[i];
        int s = src[i];
        int k = d >> 8;
        int r = base[k] + atomicAdd(&cnt2[k], 1);
        if (r < cap) part[(size_t)k * cap + r] = ((uint)d << 16) | (uint)s;
    }
}

// ---------------------------------------------------------------------------
// CSR build phase 2 (+fused GEMM1 tail blocks, which only depend on x/wt1).
// Blocks [0,nbuck): per-bucket counting sort -> rowptr, dis, csr.
// Blocks [nbuck, nbuck+ggrid): gemm1 (x fp32 -> bufA bf16).
// ---------------------------------------------------------------------------
__global__ __launch_bounds__(256) void k_sort_gemm1(const uint* __restrict__ part,
                                                    const int* __restrict__ gcur,
                                                    int nbuck, int cap, int n,
                                                    int* __restrict__ rowptr,
                                                    float* __restrict__ dis,
                                                    int* __restrict__ csr,
                                                    const float* __restrict__ x,
                                                    const ushort* __restrict__ wt1,
                                                    ushort* __restrict__ bufA) {
    __shared__ char smem[(64 + 128) * 136 * 2];  // 52.2 KB union
    const int tid = threadIdx.x;

    if ((int)blockIdx.x >= nbuck) {
        gemm_body<128, true>(x, wt1, bufA, n, blockIdx.x - nbuck, smem);
        return;
    }

    int* hist  = (int*)smem;          // 256 ints
    int* pfx   = hist + 256;
    int* sscan = pfx + 256;
    const int b = blockIdx.x;

    int gv = (tid < nbuck) ? min(gcur[tid], cap) : 0;
    sscan[tid] = gv;
    __syncthreads();
    for (int off = 1; off < 256; off <<= 1) {
        int t = (tid >= off) ? sscan[tid - off] : 0;
        __syncthreads();
        sscan[tid] += t;
        __syncthreads();
    }
    const int outbase = (b == 0) ? 0 : sscan[b - 1];
    const int sz = min(gcur[b], cap);
    const uint* seg = part + (size_t)b * cap;

    hist[tid] = 0;
    __syncthreads();
    for (int i = tid; i < sz; i += 256) atomicAdd(&hist[(seg[i] >> 16) & 255], 1);
    __syncthreads();

    int cnt_t = hist[tid];
    pfx[tid] = cnt_t;
    __syncthreads();
    for (int off = 1; off < 256; off <<= 1) {
        int t = (tid >= off) ? pfx[tid - off] : 0;
        __syncthreads();
        pfx[tid] += t;
        __syncthreads();
    }
    int excl = pfx[tid] - cnt_t;

    int node = b * 256 + tid;
    if (node < n) {
        rowptr[node] = outbase + excl;
        dis[node] = rsqrtf((float)(cnt_t + 1));  // +1 self loop
        if (node == n - 1) rowptr[n] = outbase + excl + cnt_t;
    }
    __syncthreads();
    pfx[tid] = excl;
    hist[tid] = 0;
    __syncthreads();
    for (int i = tid; i < sz; i += 256) {
        uint p = seg[i];
        int j = (p >> 16) & 255;
        int r = atomicAdd(&hist[j], 1);
        csr[outbase + pfx[j] + r] = (int)(p & 0xffffu);
    }
}

// ---------------------------------------------------------------------------
// Fused agg128 + GEMM: one block = 64 nodes, 512 threads = 8 waves.
// Stage A: 8 waves x 8 nodes each -> relu(dv*(sum dis*H) + b) into LDS A-tile
//          (bf16, 136-short padded rows). 8 nodes/wave keeps all 782 blocks
//          co-resident -> ~24 active waves/CU for gather latency hiding.
// Stage B: MFMA 64x[COLS] split across 8 waves (2 row-blocks x COLS/4 cols
//          each); B-fragments straight from global Wt (32 KB, L2-hot).
// ---------------------------------------------------------------------------
template <int COLS>
__global__ __launch_bounds__(512) void agg_gemm(const ushort* __restrict__ H,
                                                const float* __restrict__ dis,
                                                const int* __restrict__ rowptr,
                                                const int* __restrict__ csr,
                                                const float* __restrict__ bias,
                                                const ushort* __restrict__ Wt,
                                                ushort* __restrict__ Y, int n) {
    __shared__ ushort sX[64 * 136];  // 17408 B
    const int tid = threadIdx.x;
    const int wv = tid >> 6;    // 0..7
    const int lane = tid & 63;
    const int row0 = blockIdx.x * 64;
    const uint* Hu = (const uint*)H;  // row = 64 uints (128 bf16)
    const float2 bv = ((const float2*)bias)[lane];

#pragma unroll 1
    for (int i = 0; i < 8; ++i) {
        const int lr = wv * 8 + i;
        const int v = min(row0 + lr, n - 1);  // clamp: dup rows discarded at write
        const float dv = dis[v];
        const int e0 = rowptr[v];
        const int e1 = rowptr[v + 1];
        uint h0 = Hu[(size_t)v * 64 + lane];
        float ax = dv * bf_lo(h0), ay = dv * bf_hi(h0);

        int e = e0;
        while (e < e1) {
            const int c = min(e1 - e, 64);
            int sidx = 0; float sw = 0.0f;
            if (lane < c) { sidx = csr[e + lane]; sw = dis[sidx]; }
            int j = 0;
            for (; j + 16 <= c; j += 16) {
                uint hv[16]; float wgt[16];
#pragma unroll
                for (int u = 0; u < 16; ++u) {
                    int s = __builtin_amdgcn_readlane(sidx, j + u);
                    wgt[u] = lane_bcast_f(sw, j + u);
                    hv[u] = Hu[(size_t)s * 64 + lane];
                }
#pragma unroll
                for (int u = 0; u < 16; ++u) { ax += wgt[u] * bf_lo(hv[u]); ay += wgt[u] * bf_hi(hv[u]); }
            }
            for (; j + 4 <= c; j += 4) {
                uint hv[4]; float wgt[4];
#pragma unroll
                for (int u = 0; u < 4; ++u) {
                    int s = __builtin_amdgcn_readlane(sidx, j + u);
                    wgt[u] = lane_bcast_f(sw, j + u);
                    hv[u] = Hu[(size_t)s * 64 + lane];
                }
#pragma unroll
                for (int u = 0; u < 4; ++u) { ax += wgt[u] * bf_lo(hv[u]); ay += wgt[u] * bf_hi(hv[u]); }
            }
            for (; j < c; ++j) {
                int s = __builtin_amdgcn_readlane(sidx, j);
                float wg = lane_bcast_f(sw, j);
                uint hh = Hu[(size_t)s * 64 + lane];
                ax += wg * bf_lo(hh); ay += wg * bf_hi(hh);
            }
            e += c;
        }

        float rx = fmaxf(dv * ax + bv.x, 0.f);
        float ry = fmaxf(dv * ay + bv.y, 0.f);
        ((uint*)sX)[lr * 68 + lane] = (uint)f2bf(rx) | ((uint)f2bf(ry) << 16);
    }
    __syncthreads();

    // Stage B: 8 waves cover 64 rows x COLS cols.
    constexpr int NT = COLS / 64;      // 2 (COLS=128) or 1 (COLS=64)
    constexpr int WN = COLS / 4;       // cols per wave
    const int wr = wv >> 2;            // 0..1
    const int wc = wv & 3;             // 0..3
    const int lm = lane & 15;
    const int kq = lane >> 4;

    f32x4 acc[2][NT];
#pragma unroll
    for (int mt = 0; mt < 2; ++mt)
#pragma unroll
        for (int ntn = 0; ntn < NT; ++ntn) acc[mt][ntn] = (f32x4){0.f, 0.f, 0.f, 0.f};

#pragma unroll
    for (int ks = 0; ks < 4; ++ks) {
        const int k0 = ks * 32 + kq * 8;
        short8 bfr[NT];
#pragma unroll
        for (int ntn = 0; ntn < NT; ++ntn)
            bfr[ntn] = *(const short8*)&Wt[(size_t)(wc * WN + ntn * 16 + lm) * 128 + k0];
#pragma unroll
        for (int mt = 0; mt < 2; ++mt) {
            short8 afr = *(const short8*)&sX[((wr * 2 + mt) * 16 + lm) * 136 + k0];
#pragma unroll
            for (int ntn = 0; ntn < NT; ++ntn)
                acc[mt][ntn] = __builtin_amdgcn_mfma_f32_16x16x32_bf16(afr, bfr[ntn], acc[mt][ntn], 0, 0, 0);
        }
    }

#pragma unroll
    for (int mt = 0; mt < 2; ++mt) {
        int r_base = row0 + (wr * 2 + mt) * 16 + kq * 4;
#pragma unroll
        for (int ntn = 0; ntn < NT; ++ntn) {
            int col = wc * WN + ntn * 16 + lm;
#pragma unroll
            for (int rr = 0; rr < 4; ++rr) {
                int r = r_base + rr;
                if (r < n) Y[(size_t)r * COLS + col] = f2bf(acc[mt][ntn][rr]);
            }
        }
    }
}

// ---------------------------------------------------------------------------
// agg64 + row-normalize (final GCN layer), target_mlp fused as tail blocks.
// ---------------------------------------------------------------------------
__global__ __launch_bounds__(256) void agg64_final(const ushort* __restrict__ H,
                                                   const float* __restrict__ dis,
                                                   const int* __restrict__ rowptr,
                                                   const int* __restrict__ csr,
                                                   const float* __restrict__ bias,
                                                   float* __restrict__ out, int n, int agrid,
                                                   const float* __restrict__ y,
                                                   const float* __restrict__ gamma,
                                                   const float* __restrict__ beta,
                                                   const float* __restrict__ Wm1,
                                                   const float* __restrict__ bm1,
                                                   const float* __restrict__ Wm2,
                                                   const float* __restrict__ bm2,
                                                   float* __restrict__ out_y) {
    __shared__ float red[256];
    __shared__ float t1[128];
    __shared__ float s_mu, s_var;
    const int tid = threadIdx.x;

    if ((int)blockIdx.x >= agrid) {
        float yv = y[tid];
        red[tid] = yv;
        __syncthreads();
        for (int s = 128; s > 0; s >>= 1) {
            if (tid < s) red[tid] += red[tid + s];
            __syncthreads();
        }
        if (tid == 0) s_mu = red[0] * (1.0f / 256.0f);
        __syncthreads();
        float mu = s_mu;
        float d = yv - mu;
        red[tid] = d * d;
        __syncthreads();
        for (int s = 128; s > 0; s >>= 1) {
            if (tid < s) red[tid] += red[tid + s];
            __syncthreads();
        }
        if (tid == 0) s_var = red[0] * (1.0f / 256.0f);
        __syncthreads();

        const int row = blockIdx.x - agrid;
        float yb = (y[row] - mu) * rsqrtf(s_var + 1e-5f) * gamma[0] + beta[0];
        if (tid < 128) t1[tid] = fmaxf(yb * Wm1[tid] + bm1[tid], 0.0f);
        __syncthreads();
        if (tid < 64) {
            float acc = bm2[tid];
#pragma unroll 8
            for (int c = 0; c < 128; ++c) acc += t1[c] * Wm2[c * 64 + tid];
            float ss = acc * acc;
#pragma unroll
            for (int m = 1; m < 64; m <<= 1) ss += __shfl_xor(ss, m, 64);
            out_y[row * 64 + tid] = acc / fmaxf(sqrtf(ss), 1e-12f);
        }
        return;
    }

    const int wid = blockIdx.x * 4 + (tid >> 6);
    const int lane = tid & 63;
    if (wid >= n) return;
    const int v = wid;
    const float dv = dis[v];
    const int e0 = rowptr[v];
    const int e1 = rowptr[v + 1];

    float acc = dv * bf_lo((uint)H[(size_t)v * 64 + lane]);

    int e = e0;
    while (e < e1) {
        const int c = min(e1 - e, 64);
        int sidx = 0; float sw = 0.0f;
        if (lane < c) { sidx = csr[e + lane]; sw = dis[sidx]; }
        int j = 0;
        for (; j + 16 <= c; j += 16) {
            ushort hv[16]; float w[16];
#pragma unroll
            for (int u = 0; u < 16; ++u) {
                int s = __builtin_amdgcn_readlane(sidx, j + u);
                w[u] = lane_bcast_f(sw, j + u);
                hv[u] = H[(size_t)s * 64 + lane];
            }
#pragma unroll
            for (int u = 0; u < 16; ++u) acc += w[u] * bf_lo((uint)hv[u]);
        }
        for (; j < c; ++j) {
            int s = __builtin_amdgcn_readlane(sidx, j);
            float w = lane_bcast_f(sw, j);
            acc += w * bf_lo((uint)H[(size_t)s * 64 + lane]);
        }
        e += c;
    }

    float r = dv * acc + bias[lane];
    float ss = r * r;
#pragma unroll
    for (int m = 1; m < 64; m <<= 1) ss += __shfl_xor(ss, m, 64);
    r = r / fmaxf(sqrtf(ss), 1e-12f);
    out[(size_t)v * 64 + lane] = r;
}

// ---------------------------------------------------------------------------
extern "C" void kernel_launch(void* const* d_in, const int* in_sizes, int n_in,
                              void* d_out, int out_size, void* d_ws, size_t ws_size,
                              hipStream_t stream) {
    const float* x     = (const float*)d_in[0];
    const float* y     = (const float*)d_in[1];
    const int*   edge  = (const int*)d_in[2];
    const float* W1    = (const float*)d_in[3];
    const float* b1    = (const float*)d_in[4];
    const float* W2    = (const float*)d_in[5];
    const float* b2    = (const float*)d_in[6];
    const float* W3    = (const float*)d_in[7];
    const float* b3    = (const float*)d_in[8];
    const float* bng   = (const float*)d_in[9];
    const float* bnb   = (const float*)d_in[10];
    const float* Wm1   = (const float*)d_in[11];
    const float* bm1   = (const float*)d_in[12];
    const float* Wm2   = (const float*)d_in[13];
    const float* bm2   = (const float*)d_in[14];

    const int n = in_sizes[0] / 128;  // 50000
    const int E = in_sizes[2] / 2;    // 800000
    const int* src = edge;
    const int* dst = edge + E;

    const int nbuck = (n + 255) / 256;                 // 196
    const int cap = E / nbuck + E / nbuck / 4 + 1024;  // mean + 25% + slack

    size_t off = 0;
    auto carve = [&](size_t bytes) {
        size_t p = off;
        off = (off + bytes + 255) & ~(size_t)255;
        return p;
    };
    char* ws = (char*)d_ws;
    int*    gcur    = (int*)(ws + carve(256 * 4));
    uint*   part    = (uint*)(ws + carve((size_t)nbuck * cap * 4));
    int*    rowptr  = (int*)(ws + carve((size_t)(n + 1) * 4));
    int*    csr     = (int*)(ws + carve((size_t)E * 4));
    float*  dis     = (float*)(ws + carve((size_t)n * 4));
    ushort* wt1     = (ushort*)(ws + carve(128 * 128 * 2));
    ushort* wt2     = (ushort*)(ws + carve(128 * 128 * 2));
    ushort* wt3     = (ushort*)(ws + carve(64 * 128 * 2));
    ushort* bufA    = (ushort*)(ws + carve((size_t)n * 128 * 2));
    ushort* bufB    = (ushort*)(ws + carve((size_t)n * 128 * 2));
    ushort* bufC    = (ushort*)(ws + carve((size_t)n * 64 * 2));
    (void)ws_size; (void)n_in; (void)out_size;

    float* x_emb = (float*)d_out;
    float* y_emb = (float*)d_out + (size_t)n * 64;

    const int pblocks = (E + PCHUNK - 1) / PCHUNK;  // 196
    const int ggrid = (n + 63) / 64;                // 782
    const int agrid = (n + 3) / 4;                  // 12500

    hipMemsetAsync(gcur, 0, 256 * 4, stream);
    k_partition<<<pblocks + 160, 256, 0, stream>>>(src, dst, E, nbuck, cap, pblocks,
                                                   gcur, part, W1, W2, W3, wt1, wt2, wt3);
    // bucket sort (196 blocks) + gemm1 (782 blocks) run concurrently:
    // gemm1 depends only on x and wt1 (ready); sort feeds the aggs.
    k_sort_gemm1<<<nbuck + ggrid, 256, 0, stream>>>(part, gcur, nbuck, cap, n,
                                                    rowptr, dis, csr, x, wt1, bufA);

    // fused: agg(layer1 out, +b1, relu) -> GEMM W2  => bufB   (512 thr/block)
    agg_gemm<128><<<ggrid, 512, 0, stream>>>(bufA, dis, rowptr, csr, b1, wt2, bufB, n);
    // fused: agg(layer2 out, +b2, relu) -> GEMM W3  => bufC
    agg_gemm<64><<<ggrid, 512, 0, stream>>>(bufB, dis, rowptr, csr, b2, wt3, bufC, n);
    // final agg + normalize (+ target MLP tail blocks)
    agg64_final<<<agrid + 256, 256, 0, stream>>>(bufC, dis, rowptr, csr, b3, x_emb, n, agrid,
                                                 y, bng, bnb, Wm1, bm1, Wm2, bm2, y_emb);
}